// Round 1
// 3240.738 us; speedup vs baseline: 1.0440x; 1.0440x over previous
//
#include <hip/hip_runtime.h>

// GraphProject: out[b,n,:] = [xyz(3) | bilerp(feat0,64) | bilerp(feat1,128)
//                             | bilerp(feat2,256) | bilerp(feat3,512)]  (963 ch)
// proj_mat is unused by the reference.
//
// Key observation: every bilinear weight contains both an x-factor and a
// y-factor, so when floor(x)==ceil(x) OR floor(y)==ceil(y) (true for any
// clamped coordinate -> ~93% of (vertex,scale) pairs for N(0,1) inputs,
// since h,w are Cauchy-distributed), ALL four weights are exactly zero and
// the output block is 0. We skip the gathers entirely in that case.
//
// Store mapping: store-instruction k writes channel 3 + 240*k + t, so each
// wave-level store is a fully dense contiguous burst (240 lanes x 4B),
// instead of 4 stride-16B sparse scalar stores per thread.

#define VPB 4  // vertices per block

// ---- prepass: (B,C,S,S) -> (B,S,S,C) channel-last for coalesced gathers ----
template<int C, int S>
__global__ __launch_bounds__(256) void transpose_feat(const float* __restrict__ src,
                                                      float* __restrict__ dst,
                                                      int total) {
    int i = blockIdx.x * 256 + threadIdx.x;
    if (i >= total) return;
    int c  = i % C;        // C pow2 -> and
    int p  = i / C;        // pow2 -> shift
    int w  = p % S;        // compile-time magic div
    int p2 = p / S;
    int h  = p2 % S;
    int b  = p2 / S;
    dst[i] = src[((b * C + c) * S + h) * S + w];
}

// ---- main: per-vertex projection + 4-scale bilinear gather ----
__global__ __launch_bounds__(256) void gp_main(const float* __restrict__ verts,
                                               const float* __restrict__ f0,
                                               const float* __restrict__ f1,
                                               const float* __restrict__ f2,
                                               const float* __restrict__ f3,
                                               float* __restrict__ out,
                                               int N, int total_v) {
    __shared__ float swt[VPB][4][4];  // w11,w12,w21,w22 per (vert, scale)
    __shared__ int   sof[VPB][4][4];  // corner element offsets (pre-mult by C)
    __shared__ int   snz[VPB][4];     // nonzero flag per (vert, scale)
    __shared__ float sv[VPB][3];      // xyz passthrough

    const int t  = threadIdx.x;
    const int v0 = blockIdx.x * VPB;

    if (t < VPB * 4) {
        const int v  = t >> 2;
        const int sc = t & 3;
        const int vi = v0 + v;
        if (vi < total_v) {
            const int b = vi / N;
            const float X = verts[3 * vi + 0];
            const float Y = verts[3 * vi + 1];
            const float Z = verts[3 * vi + 2];
            if (sc == 0) { sv[v][0] = X; sv[v][1] = Y; sv[v][2] = Z; }
            // h = FY*(Y/Z)+CY ; w = FX*(X/-Z)+CX  -- exact rn ops, no contraction
            const float h = __fadd_rn(__fmul_rn(250.0f, __fdiv_rn(Y, Z)), 112.0f);
            const float w = __fadd_rn(__fmul_rn(250.0f, __fdiv_rn(X, -Z)), 112.0f);

            const int   Sarr[4] = {56, 28, 14, 7};
            const int   Carr[4] = {64, 128, 256, 512};
            const float invA[4] = {0.25f, 0.125f, 0.0625f, 0.03125f};
            const int s  = Sarr[sc];
            const int Cc = Carr[sc];
            const float smax = (float)(s - 1);

            const float x = fminf(fmaxf(__fmul_rn(h, invA[sc]), 0.0f), smax);
            const float y = fminf(fmaxf(__fmul_rn(w, invA[sc]), 0.0f), smax);
            const float x1f = floorf(x), x2f = ceilf(x);
            const float y1f = floorf(y), y2f = ceilf(y);
            const int x1 = (int)x1f, x2 = (int)x2f;
            const int y1 = (int)y1f, y2 = (int)y2f;

            swt[v][sc][0] = (x2f - x) * (y2f - y);  // w11
            swt[v][sc][1] = (x2f - x) * (y - y1f);  // w12
            swt[v][sc][2] = (x - x1f) * (y2f - y);  // w21
            swt[v][sc][3] = (x - x1f) * (y - y1f);  // w22

            // all four weights are products with both an x- and y-factor:
            // if x or y is integral (incl. any clamp), result is exactly 0.
            snz[v][sc] = (x1 != x2) && (y1 != y2);

            const int base = b * s * s;
            sof[v][sc][0] = (base + x1 * s + y1) * Cc;
            sof[v][sc][1] = (base + x1 * s + y2) * Cc;
            sof[v][sc][2] = (base + x2 * s + y1) * Cc;
            sof[v][sc][3] = (base + x2 * s + y2) * Cc;
        }
    }
    __syncthreads();

    // per-thread per-k channel mapping: store instr k covers channel 3+240k+t
    // (lane-contiguous => dense stores AND dense scalar corner loads)
    int   sck[4], cik[4];
    const float* fpk[4];
    if (t < 240) {
#pragma unroll
        for (int k = 0; k < 4; ++k) {
            const int c = 3 + 240 * k + t;
            if (c < 67)       { sck[k] = 0; cik[k] = c - 3;   fpk[k] = f0; }
            else if (c < 195) { sck[k] = 1; cik[k] = c - 67;  fpk[k] = f1; }
            else if (c < 451) { sck[k] = 2; cik[k] = c - 195; fpk[k] = f2; }
            else              { sck[k] = 3; cik[k] = c - 451; fpk[k] = f3; }
        }
    }

    for (int v = 0; v < VPB; ++v) {
        const int vi = v0 + v;
        if (vi >= total_v) break;
        const size_t obase = (size_t)vi * 963;
        if (t < 240) {
#pragma unroll
            for (int k = 0; k < 4; ++k) {
                const int sc = sck[k];
                float r = 0.0f;
                if (snz[v][sc]) {
                    const float w11 = swt[v][sc][0], w12 = swt[v][sc][1];
                    const float w21 = swt[v][sc][2], w22 = swt[v][sc][3];
                    const float* fp = fpk[k];
                    const int ci = cik[k];
                    const float q11 = fp[sof[v][sc][0] + ci];
                    const float q12 = fp[sof[v][sc][1] + ci];
                    const float q21 = fp[sof[v][sc][2] + ci];
                    const float q22 = fp[sof[v][sc][3] + ci];
                    // ref order: w11*Q11 + w21*Q21 + w12*Q12 + w22*Q22
                    r = w11 * q11 + w21 * q21 + w12 * q12 + w22 * q22;
                }
                out[obase + 3 + 240 * k + t] = r;
            }
        } else if (t < 243) {
            out[obase + (t - 240)] = sv[v][t - 240];
        }
    }
}

extern "C" void kernel_launch(void* const* d_in, const int* in_sizes, int n_in,
                              void* d_out, int out_size, void* d_ws, size_t ws_size,
                              hipStream_t stream) {
    const float* verts = (const float*)d_in[0];
    const float* f0s   = (const float*)d_in[1];
    const float* f1s   = (const float*)d_in[2];
    const float* f2s   = (const float*)d_in[3];
    const float* f3s   = (const float*)d_in[4];
    // d_in[5] (proj_mat) unused by reference

    const int B = in_sizes[5] / 16;          // proj is B*4*4
    const int N = in_sizes[0] / (3 * B);
    const int total_v = B * N;

    const int n0 = B * 64 * 56 * 56;
    const int n1 = B * 128 * 28 * 28;
    const int n2 = B * 256 * 14 * 14;
    const int n3 = B * 512 * 7 * 7;

    float* t0 = (float*)d_ws;
    float* t1 = t0 + n0;
    float* t2 = t1 + n1;
    float* t3 = t2 + n2;

    transpose_feat<64, 56><<<(n0 + 255) / 256, 256, 0, stream>>>(f0s, t0, n0);
    transpose_feat<128, 28><<<(n1 + 255) / 256, 256, 0, stream>>>(f1s, t1, n1);
    transpose_feat<256, 14><<<(n2 + 255) / 256, 256, 0, stream>>>(f2s, t2, n2);
    transpose_feat<512, 7><<<(n3 + 255) / 256, 256, 0, stream>>>(f3s, t3, n3);

    const int nblocks = (total_v + VPB - 1) / VPB;
    gp_main<<<nblocks, 256, 0, stream>>>(verts, t0, t1, t2, t3,
                                         (float*)d_out, N, total_v);
}